// Round 16
// baseline (155.751 us; speedup 1.0000x reference)
//
#include <hip/hip_runtime.h>
#if __has_include(<hip/hip_fp8.h>)
#include <hip/hip_fp8.h>
#endif

// ---------------------------------------------------------------------------
// MHABlock (4 dispatches): QKV GEMM staging fp32 DIRECTLY via global_load_lds
// (cvt dispatch deleted; sqrt-softmax-scale applied in epilogue to Q and K) ->
// fused K/V transpose + fp8 convert (+Q->fp8, +vals zero, +l_tot zero) ->
// split-K(3) fp8 flash attention (R14 2-barrier ping-pong, R10 layouts) ->
// deferred normalize + residual + LayerNorm.
// ---------------------------------------------------------------------------

typedef __bf16 bf16x8 __attribute__((ext_vector_type(8)));
typedef __bf16 bf16x4 __attribute__((ext_vector_type(4)));
typedef float  f32x4  __attribute__((ext_vector_type(4)));
typedef float  f32x8  __attribute__((ext_vector_type(8)));
typedef unsigned short u16x4 __attribute__((ext_vector_type(4)));
typedef unsigned int   u32x4 __attribute__((ext_vector_type(4)));
typedef long           la64  __attribute__((may_alias));
typedef unsigned int   ua32  __attribute__((may_alias));
typedef float          laf4  __attribute__((ext_vector_type(4), aligned(16))) ;

#define N_TOK   4096
#define D_MODEL 640
#define DK      64
#define HSLAB   (N_TOK * DK)
// sqrt(log2(e)/64): applied in gemm epilogue to BOTH Q and K outputs
#define SQS 0.15014030f

#if __has_builtin(__builtin_amdgcn_exp2f)
#define EXP2(x) __builtin_amdgcn_exp2f(x)
#else
#define EXP2(x) exp2f(x)
#endif

__device__ __forceinline__ void stage16(const void* g, void* lds_uniform) {
    __builtin_amdgcn_global_load_lds(
        (const __attribute__((address_space(1))) unsigned int*)g,
        (__attribute__((address_space(3))) unsigned int*)lds_uniform, 16, 0, 0);
}

__device__ __forceinline__ u16x4 cvt4(f32x4 v) {
    return __builtin_bit_cast(u16x4, __builtin_convertvector(v, bf16x4));
}

__device__ __forceinline__ bf16x8 pack8(f32x4 lo, f32x4 hi) {
    f32x8 c;
    c[0] = lo[0]; c[1] = lo[1]; c[2] = lo[2]; c[3] = lo[3];
    c[4] = hi[0]; c[5] = hi[1]; c[6] = hi[2]; c[7] = hi[3];
    return __builtin_convertvector(c, bf16x8);
}

__device__ __forceinline__ unsigned int pk_fp8(f32x4 v) {
#if __has_builtin(__builtin_amdgcn_cvt_pk_fp8_f32)
    int r = 0;
    r = __builtin_amdgcn_cvt_pk_fp8_f32(v[0], v[1], r, false);
    r = __builtin_amdgcn_cvt_pk_fp8_f32(v[2], v[3], r, true);
    return (unsigned int)r;
#else
    union { unsigned char b[4]; unsigned int u; } x;
    x.b[0] = __hip_fp8_e4m3(v[0]).__x;
    x.b[1] = __hip_fp8_e4m3(v[1]).__x;
    x.b[2] = __hip_fp8_e4m3(v[2]).__x;
    x.b[3] = __hip_fp8_e4m3(v[3]).__x;
    return x.u;
#endif
}

// ------------------------ QKV NT-GEMM: C = x @ W^T -------------------------
// M=4096, N=640, K=640. 128x128 tile, BK=64, 4 waves each 64x64.
// fp32 staged directly (chunk=16B=4 floats, 16 units/row, XOR-unit swizzle);
// fragments ds_read_b128 x2 -> packed cvt to bf16. Q/K scaled in epilogue.
// Grid 480 linear, XCD-pinned m-tiles (g = b&31).
__global__ __launch_bounds__(256, 2) void gemm_qkv(
    const float* __restrict__ xf,
    const float* __restrict__ wq,
    const float* __restrict__ wk,
    const float* __restrict__ wv,
    unsigned short* __restrict__ Qo,
    unsigned short* __restrict__ Ko,
    unsigned short* __restrict__ Vo) {
    const int b = blockIdx.x;
    const int g = b & 31;            // m-tile (XCD-pinned)
    const int r = b >> 5;            // 0..14 = (mode, n-tile)
    const int mode = r / 5;
    const int m0 = g * 128;
    const int n0 = (r % 5) * 128;
    const float* W = (mode == 0) ? wq : (mode == 1) ? wk : wv;
    unsigned short* C = (mode == 0) ? Qo : (mode == 1) ? Ko : Vo;
    const float escale = (mode < 2) ? SQS : 1.0f;

    __shared__ float As[8192];   // 128 rows x 64 fp32 = 32KB
    __shared__ float Bs[8192];

    const int tid  = threadIdx.x;
    const int lane = tid & 63;
    const int wave = tid >> 6;
    const int quad = lane >> 4, l16 = lane & 15;
    const int wm = (wave >> 1) * 64, wn = (wave & 1) * 64;

    f32x4 acc[4][4] = {};

    // chunk c = j*256 + tid: row = c>>4, logical unit = c&15,
    // physical unit = (c&15)^(row&15). Each 16-lane group covers one 256B row.
    int prow[8], pcol[8];
    for (int j = 0; j < 8; j++) {
        int c = j * 256 + tid;
        prow[j] = c >> 4;
        pcol[j] = ((c & 15) ^ (prow[j] & 15)) * 4;   // fp32 elem offset
    }

    for (int kt = 0; kt < D_MODEL; kt += 64) {
        __syncthreads();
        for (int j = 0; j < 8; j++) {
            char* dst = (char*)As + j * 4096 + wave * 1024;
            stage16(&xf[(size_t)(m0 + prow[j]) * D_MODEL + kt + pcol[j]], dst);
            char* dstB = (char*)Bs + j * 4096 + wave * 1024;
            stage16(&W [(size_t)(n0 + prow[j]) * D_MODEL + kt + pcol[j]], dstB);
        }
        __syncthreads();

        for (int s = 0; s < 2; s++) {
            const int u0 = s * 8 + quad * 2;
            bf16x8 af[4], bfr[4];
            for (int mi = 0; mi < 4; mi++) {
                int row = wm + mi * 16 + l16;
                int r15 = row & 15;
                const float* base = As + row * 64;
                f32x4 lo = *(const laf4*)(base + ((u0     ^ r15) * 4));
                f32x4 hi = *(const laf4*)(base + (((u0+1) ^ r15) * 4));
                af[mi] = pack8(lo, hi);
            }
            for (int ni = 0; ni < 4; ni++) {
                int row = wn + ni * 16 + l16;
                int r15 = row & 15;
                const float* base = Bs + row * 64;
                f32x4 lo = *(const laf4*)(base + ((u0     ^ r15) * 4));
                f32x4 hi = *(const laf4*)(base + (((u0+1) ^ r15) * 4));
                bfr[ni] = pack8(lo, hi);
            }
            for (int mi = 0; mi < 4; mi++)
                for (int ni = 0; ni < 4; ni++)
                    acc[mi][ni] = __builtin_amdgcn_mfma_f32_16x16x32_bf16(af[mi], bfr[ni], acc[mi][ni], 0, 0, 0);
        }
    }

    for (int mi = 0; mi < 4; mi++)
        for (int ni = 0; ni < 4; ni++) {
            f32x4 a = acc[mi][ni];
            a[0] *= escale; a[1] *= escale; a[2] *= escale; a[3] *= escale;
            u16x4 cv = cvt4(a);
            for (int r2 = 0; r2 < 4; r2++) {
                int row = m0 + wm + mi * 16 + quad * 4 + r2;
                int col = n0 + wn + ni * 16 + l16;
                C[(size_t)row * D_MODEL + col] = cv[r2];
            }
        }
}

// ------ fused per-head transpose -> fp8 (K',V') + Q->fp8 + zeroing ---------
// z<10: K head z [64][4096]->fp8 [4096][64]; z in [10,20): V head z-10
// [4096][64]->fp8 [64][4096]; z in [20,30): Q head z-20 bf16->fp8 flat,
// plus l_tot zeroing (t<16). Source tiles zeroed after read (= vals buffer).
__global__ __launch_bounds__(256) void transpose_kv(
    const unsigned short* __restrict__ Kn, unsigned char* __restrict__ Kp8,
    const unsigned short* __restrict__ Vn, unsigned char* __restrict__ Vp8,
    const unsigned short* __restrict__ Qn, unsigned char* __restrict__ Qf8,
    f32x4* __restrict__ ltot4) {
    const int z = blockIdx.z;
    const int t = threadIdx.x;

    if (z >= 20) {   // Q convert + l_tot zero
        const int hq = z - 20;
        if (t < 16)
            ltot4[hq * 1024 + blockIdx.x * 16 + t] = (f32x4){0.f, 0.f, 0.f, 0.f};
        const size_t base = (size_t)hq * HSLAB + blockIdx.x * 4096 + t * 16;
        bf16x8 v0 = *(const bf16x8*)&Qn[base];
        bf16x8 v1 = *(const bf16x8*)&Qn[base + 8];
        f32x4 a = {(float)v0[0], (float)v0[1], (float)v0[2], (float)v0[3]};
        f32x4 b = {(float)v0[4], (float)v0[5], (float)v0[6], (float)v0[7]};
        f32x4 c = {(float)v1[0], (float)v1[1], (float)v1[2], (float)v1[3]};
        f32x4 d = {(float)v1[4], (float)v1[5], (float)v1[6], (float)v1[7]};
        u32x4 o = {pk_fp8(a), pk_fp8(b), pk_fp8(c), pk_fp8(d)};
        *(u32x4*)&Qf8[base] = o;
        return;
    }

    __shared__ unsigned short T[64][66];
    const unsigned short* src; unsigned char* dst;
    int R, Cc, r0, c0;
    if (z < 10) { src = Kn; dst = Kp8; R = 64;   Cc = 4096; r0 = 0; c0 = blockIdx.x * 64; }
    else        { src = Vn; dst = Vp8; R = 4096; Cc = 64;   r0 = blockIdx.x * 64; c0 = 0; }
    const size_t hb = (size_t)(z % 10) * HSLAB;
    const int rr = t >> 3, c8 = (t & 7) * 8;

    for (int hf = 0; hf < 2; hf++) {
        int r = rr + hf * 32;
        bf16x8 v = *(const bf16x8*)&src[hb + (size_t)(r0 + r) * Cc + c0 + c8];
        for (int j = 0; j < 8; j++) T[r][c8 + j] = ((unsigned short*)&v)[j];
    }
    __syncthreads();
    const bf16x8 zz = {};
    for (int hf = 0; hf < 2; hf++) {
        int r = rr + hf * 32;
        *(bf16x8*)&((unsigned short*)src)[hb + (size_t)(r0 + r) * Cc + c0 + c8] = zz;
    }
    for (int hf = 0; hf < 2; hf++) {
        int oc = rr + hf * 32;
        f32x4 lo, hi;
        for (int j = 0; j < 4; j++) {
            lo[j] = __builtin_bit_cast(float, (unsigned int)T[c8 + j][oc] << 16);
            hi[j] = __builtin_bit_cast(float, (unsigned int)T[c8 + 4 + j][oc] << 16);
        }
        uint2 ov; ov.x = pk_fp8(lo); ov.y = pk_fp8(hi);
        size_t dcol = (z < 10) ? ((size_t)(c0 + oc) * 64 + r0 + c8)
                               : ((size_t)oc * 4096 + r0 + c8);
        *(uint2*)&dst[hb + dcol] = ov;
    }
}

// ------------------------------- attention (fp8) ---------------------------
// grid (320, 3). R14 structure: 2 barriers/tile, ping-pong K, V under S.
__global__ __launch_bounds__(256, 4) void attn(
    const unsigned char* __restrict__ Qf8,   // [h][q][dk] fp8
    const unsigned char* __restrict__ Kp8,   // [h][key][dk] fp8
    const unsigned char* __restrict__ Vp8,   // [h][dk][key] fp8
    float* __restrict__ vals,                // pre-zeroed (transpose_kv)
    float* __restrict__ l_tot) {             // pre-zeroed (transpose_kv)
    const int h  = blockIdx.x >> 5;
    const int qt = blockIdx.x & 31;
    const int ntile = (blockIdx.y == 2) ? 10 : 11;
    const int tile0 = blockIdx.y * 11;
    const int lane = threadIdx.x & 63;
    const int wave = threadIdx.x >> 6;
    const int quad = lane >> 4, l16 = lane & 15;
    const size_t hoff = (size_t)h * HSLAB;

    __shared__ unsigned char sm[40960];
    unsigned char* const Kb0 = sm;                      // 8KB, ping
    unsigned char* const Kb1 = sm + 8192;               // 8KB, pong
    unsigned char* const Vt  = sm + 16384;              // 8KB
    unsigned char* const Pw  = sm + 24576 + wave * 4096;// 4KB/wave

    const int qbase = qt * 128 + wave * 32;
    long qd[2][2];
    for (int g = 0; g < 2; g++) {
        const unsigned char* qp = Qf8 + hoff + (size_t)(qbase + g * 16 + l16) * 64 + quad * 8;
        qd[g][0] = *(const la64*)(qp);
        qd[g][1] = *(const la64*)(qp + 32);
    }

    f32x4 o[2][4] = {};
    f32x4 ol[2] = {};
    const long ONES8 = 0x3838383838383838L;   // e4m3 1.0 x8

    const int cA = wave * 64 + lane, cB = cA + 256;
    const int kKeyA = ((cA >> 5) << 3) + (cA & 7), kCiA = (cA >> 3) & 3;
    const int kKeyB = ((cB >> 5) << 3) + (cB & 7), kCiB = (cB >> 3) & 3;
    const int vDkA  = ((cA >> 6) << 3) + (cA & 7), vCvA = (cA >> 3) & 7;
    const int vDkB  = ((cB >> 6) << 3) + (cB & 7), vCvB = (cB >> 3) & 7;

    const int kfb = (l16 >> 3) * 512 + (quad >> 1) * 128 + (l16 & 7) * 16 + (quad & 1) * 8;
    const int vfb = (l16 >> 3) * 1024 + (quad >> 1) * 128 + (l16 & 7) * 16 + (quad & 1) * 8;

    {
        const int keyb = tile0 << 7;
        stage16(Kp8 + hoff + (size_t)(keyb + kKeyA) * 64 + kCiA * 16, Kb0 + wave * 1024);
        stage16(Kp8 + hoff + (size_t)(keyb + kKeyB) * 64 + kCiB * 16, Kb0 + 4096 + wave * 1024);
    }

    for (int t = 0; t < ntile; t++) {
        const int keyb = (tile0 + t) << 7;
        unsigned char* const Kcur = (t & 1) ? Kb1 : Kb0;

        __syncthreads();

        if (t + 1 < ntile) {
            const int keyn = (tile0 + t + 1) << 7;
            unsigned char* const Knext = (t & 1) ? Kb0 : Kb1;
            stage16(Kp8 + hoff + (size_t)(keyn + kKeyA) * 64 + kCiA * 16, Knext + wave * 1024);
            stage16(Kp8 + hoff + (size_t)(keyn + kKeyB) * 64 + kCiB * 16, Knext + 4096 + wave * 1024);
        }
        stage16(Vp8 + hoff + (size_t)vDkA * N_TOK + keyb + vCvA * 16, Vt + wave * 1024);
        stage16(Vp8 + hoff + (size_t)vDkB * N_TOK + keyb + vCvB * 16, Vt + 4096 + wave * 1024);

        for (int ni = 0; ni < 8; ni++) {
            const unsigned char* kp = Kcur + ni * 1024 + kfb;
            long a0 = *(const la64*)(kp);
            long a1 = *(const la64*)(kp + 256);
            for (int g = 0; g < 2; g++) {
                f32x4 s = {};
                s = __builtin_amdgcn_mfma_f32_16x16x32_fp8_fp8(a0, qd[g][0], s, 0, 0, 0);
                s = __builtin_amdgcn_mfma_f32_16x16x32_fp8_fp8(a1, qd[g][1], s, 0, 0, 0);
                f32x4 pv;
                for (int r = 0; r < 4; r++) pv[r] = EXP2(s[r]);
                *(ua32*)(Pw + (ni * 2 + (quad >> 1)) * 256 +
                         (g * 16 + l16) * 8 + (quad & 1) * 4) = pk_fp8(pv);
            }
        }

        __syncthreads();

        for (int ks = 0; ks < 4; ks++) {
            long vf[4];
            for (int nd = 0; nd < 4; nd++)
                vf[nd] = *(const la64*)(Vt + nd * 2048 + ks * 256 + vfb);
            for (int g = 0; g < 2; g++) {
                long pf = *(const la64*)(Pw + (ks * 4 + quad) * 256 + (g * 16 + l16) * 8);
                ol[g] = __builtin_amdgcn_mfma_f32_16x16x32_fp8_fp8(pf, ONES8, ol[g], 0, 0, 0);
                for (int nd = 0; nd < 4; nd++)
                    o[g][nd] = __builtin_amdgcn_mfma_f32_16x16x32_fp8_fp8(pf, vf[nd], o[g][nd], 0, 0, 0);
            }
        }
    }

    if (l16 == 0)
        for (int g = 0; g < 2; g++)
            for (int r = 0; r < 4; r++)
                atomicAdd(&l_tot[(h << 12) + qbase + g * 16 + quad * 4 + r], ol[g][r]);

    for (int g = 0; g < 2; g++)
        for (int nd = 0; nd < 4; nd++)
            for (int r = 0; r < 4; r++) {
                int q = qbase + g * 16 + quad * 4 + r;
                atomicAdd(&vals[hoff + (size_t)q * DK + nd * 16 + l16], o[g][nd][r]);
            }
}

// ----------------- deferred normalize + residual + LayerNorm ---------------
__global__ __launch_bounds__(256) void ln_kernel(
    const float* __restrict__ vals, const float* __restrict__ l_tot,
    const float* __restrict__ x,
    const float* __restrict__ gamma, const float* __restrict__ beta,
    float* __restrict__ out) {
    const int wave = threadIdx.x >> 6, lane = threadIdx.x & 63;
    const int row  = blockIdx.x * 4 + wave;
    const float* v  = vals + (size_t)row * D_MODEL;
    const float* xr = x    + (size_t)row * D_MODEL;

    float t[10];
    float s = 0.f;
    for (int i = 0; i < 10; i++) {
        float linv = 1.0f / l_tot[row * 10 + i];
        t[i] = v[lane + i * 64] * linv + xr[lane + i * 64];
        s += t[i];
    }
    for (int off = 32; off; off >>= 1) s += __shfl_xor(s, off, 64);
    float mean = s * (1.0f / 640.0f);
    float s2 = 0.f;
    for (int i = 0; i < 10; i++) { float d = t[i] - mean; s2 += d * d; }
    for (int off = 32; off; off >>= 1) s2 += __shfl_xor(s2, off, 64);
    float inv = rsqrtf(s2 * (1.0f / 640.0f) + 1e-5f);

    float* orow = out + (size_t)row * D_MODEL;
    for (int i = 0; i < 10; i++) {
        int c = lane + i * 64;
        orow[c] = (t[i] - mean) * inv * gamma[c] + beta[c];
    }
}

// ------------------------------- launcher ----------------------------------
extern "C" void kernel_launch(void* const* d_in, const int* in_sizes, int n_in,
                              void* d_out, int out_size, void* d_ws, size_t ws_size,
                              hipStream_t stream) {
    const float* x     = (const float*)d_in[0];
    const float* Wq    = (const float*)d_in[1];
    const float* Wk    = (const float*)d_in[2];
    const float* Wv    = (const float*)d_in[3];
    const float* gamma = (const float*)d_in[4];
    const float* beta  = (const float*)d_in[5];
    float* out = (float*)d_out;

    char* ws = (char*)d_ws;
    unsigned char*  Qf8 = (unsigned char*)(ws);                // 2,621,440 B
    unsigned short* Qn  = (unsigned short*)(ws + 7700480);     // bf16 Q natural
    unsigned char*  Kp8 = (unsigned char*)(ws + 12943360);     // fp8 K' [h][key][dk]
    unsigned char*  Vp8 = (unsigned char*)(ws + 18186240);     // fp8 V' [h][dk][key]
    unsigned short* Kn  = (unsigned short*)(ws + 23429120);    // aliases vals
    unsigned short* Vn  = (unsigned short*)(ws + 28672000);    //  (exactly)
    float*          vals  = (float*)(ws + 23429120);           // 10,485,760 B
    float*          l_tot = (float*)(ws + 33914880);           //   163,840 B

    gemm_qkv<<<480, 256, 0, stream>>>(x, Wq, Wk, Wv, Qn, Kn, Vn);

    transpose_kv<<<dim3(64, 1, 30), 256, 0, stream>>>(Kn, Kp8, Vn, Vp8, Qn, Qf8,
                                                      (f32x4*)l_tot);

    attn<<<dim3(320, 3), 256, 0, stream>>>(Qf8, Kp8, Vp8, vals, l_tot);
    ln_kernel<<<1024, 256, 0, stream>>>(vals, l_tot, x, gamma, beta, out);
}